// Round 7
// baseline (884.858 us; speedup 1.0000x reference)
//
#include <hip/hip_runtime.h>

#define BN_EPS 1e-5f

typedef __attribute__((ext_vector_type(4))) float f32x4;
typedef __attribute__((ext_vector_type(8))) short bf16x8;
typedef __attribute__((ext_vector_type(4))) unsigned short u16x4;
typedef unsigned short u16;

__device__ __forceinline__ u16 f2bf(float x) {
    union { float f; unsigned u; } v; v.f = x;
    unsigned u = v.u;
    return (u16)((u + 0x7FFFu + ((u >> 16) & 1u)) >> 16);  // round-to-nearest-even
}
__device__ __forceinline__ float bf2f(u16 b) {
    union { unsigned u; float f; } v; v.u = ((unsigned)b) << 16;
    return v.f;
}

// ---------------- setup: fold BN into scale/bias, cast weights to bf16 ----------------
__global__ __launch_bounds__(256) void k_setup(
    const float* __restrict__ W1, const float* __restrict__ g1, const float* __restrict__ b1,
    const float* __restrict__ m1, const float* __restrict__ v1,
    const float* __restrict__ Wp1, const float* __restrict__ gp1, const float* __restrict__ bp1,
    const float* __restrict__ mp1, const float* __restrict__ vp1,
    const float* __restrict__ Wp2, const float* __restrict__ gp2, const float* __restrict__ bp2,
    const float* __restrict__ mp2, const float* __restrict__ vp2,
    u16* __restrict__ W1b, u16* __restrict__ Wp1b, u16* __restrict__ Wp2b,
    float* __restrict__ cst) {
    int t = blockIdx.x * 256 + threadIdx.x;
    if (t < 4096)  W1b[t]  = f2bf(W1[t]);
    if (t < 16384) { Wp1b[t] = f2bf(Wp1[t]); Wp2b[t] = f2bf(Wp2[t]); }
    if (t < 64)  { float iv = g1[t]  / sqrtf(v1[t]  + BN_EPS); cst[t]      = iv; cst[64 + t]  = b1[t]  - m1[t]  * iv; }
    if (t < 256) { float iv = gp1[t] / sqrtf(vp1[t] + BN_EPS); cst[128 + t] = iv; cst[384 + t] = bp1[t] - mp1[t] * iv; }
    if (t < 64)  { float iv = gp2[t] / sqrtf(vp2[t] + BN_EPS); cst[640 + t] = iv; cst[704 + t] = bp2[t] - mp2[t] * iv; }
}

// ---------------- conv1: x1t[b][n][c] = bf16( relu(bn1(W1 @ f)) ) ----------------
// D-tile = [nn rows][o cols]: A = f^T (rows nn, k=c, from swizzled LDS), B = W1^T (cols o, k-contig = W1 rows).
__global__ __launch_bounds__(256) void k_conv1(
    const float* __restrict__ f, const u16* __restrict__ W1b,
    const float* __restrict__ cst, u16* __restrict__ x1tb) {
    int bid = blockIdx.x;
    int s = ((bid & 7) << 8) | (bid >> 3);   // XCD b -> batch b
    int b = s >> 8;
    int n0 = (s & 255) << 6;
    __shared__ __align__(16) u16 f_t[64 * 64];   // [nn][c] bf16, elem ^= (nn&7)<<3
    int tid = threadIdx.x;
    const float* fB = f + ((b << 6) * 16384 + n0);
    #pragma unroll
    for (int i = 0; i < 4; ++i) {
        int g = tid + (i << 8);
        int c = g >> 4, q = (g & 15) << 2;
        f32x4 v = *(const f32x4*)(fB + c * 16384 + q);
        #pragma unroll
        for (int j = 0; j < 4; ++j) {
            int nn = q + j;
            f_t[(nn << 6) + (c ^ ((nn & 7) << 3))] = f2bf(v[j]);
        }
    }
    __syncthreads();
    int lane = tid & 63, wv = tid >> 6;
    int l15 = lane & 15, kg = lane >> 4;
    int nt = wv;
    bf16x8 afr[2];
    #pragma unroll
    for (int ks = 0; ks < 2; ++ks) {
        int row = (nt << 4) + l15;
        afr[ks] = *(const bf16x8*)&f_t[(row << 6) + (((ks << 5) + (kg << 3)) ^ ((row & 7) << 3))];
    }
    #pragma unroll
    for (int ot = 0; ot < 4; ++ot) {
        f32x4 acc = {0.f, 0.f, 0.f, 0.f};
        int o = (ot << 4) + l15;
        #pragma unroll
        for (int ks = 0; ks < 2; ++ks) {
            bf16x8 bfr = *(const bf16x8*)&W1b[(o << 6) + (ks << 5) + (kg << 3)];
            acc = __builtin_amdgcn_mfma_f32_16x16x32_bf16(afr[ks], bfr, acc, 0, 0, 0);
        }
        float iv = cst[o], be = cst[64 + o];
        #pragma unroll
        for (int r = 0; r < 4; ++r) {
            int nn = (nt << 4) + (kg << 2) + r;
            float x = fmaxf(fmaf(acc[r], iv, be), 0.f);
            x1tb[((b * 16384 + n0 + nn) << 6) + o] = f2bf(x);
        }
    }
}

// ---------------- fused: gather+maxpool -> pwconv1(+bn,relu) -> pwconv2(+bn) + residual + relu ----
// Wave w owns n-rows [16w,16w+16) through all stages => all LDS use is wave-local (no barriers).
__global__ __launch_bounds__(256) void k_fused(
    const float* __restrict__ pe, const int* __restrict__ idx, const u16* __restrict__ x1tb,
    const float* __restrict__ f, const u16* __restrict__ Wp1b, const u16* __restrict__ Wp2b,
    const float* __restrict__ cst, float* __restrict__ out) {
    int bid = blockIdx.x;
    int s = ((bid & 7) << 8) | (bid >> 3);   // XCD b caches x1tb slice of batch b in its L2
    int b = s >> 8;
    int n0 = (s & 255) << 6;
    __shared__ __align__(16) u16 y_t[64 * 64];    // [nn][c]  bf16, elem ^= (nn&7)<<3   (8 KB)
    __shared__ __align__(16) u16 z_t[64 * 256];   // [nn][m]  bf16, elem ^= (nn&7)<<3   (32 KB)
    int tid = threadIdx.x;
    int lane = tid & 63, wv = tid >> 6;

    // ---- stage 1: gather + max-pool over K=16 ----
    {
        int c = lane;
        const float* peB = pe + (size_t)(((b << 6) + c) * 16384 + n0) * 16;
        const u16* xB = x1tb + ((b * 16384) << 6) + c;
        const int* idxB = idx + ((b * 16384 + n0) << 4);
        for (int nn = wv << 4; nn < (wv << 4) + 16; ++nn) {
            float mx = -3.4e38f;
            #pragma unroll
            for (int k4 = 0; k4 < 4; ++k4) {
                f32x4 pv = *(const f32x4*)(peB + (nn << 4) + (k4 << 2));
                #pragma unroll
                for (int j = 0; j < 4; ++j) {
                    int jj = idxB[(nn << 4) + (k4 << 2) + j];   // wave-uniform -> broadcast
                    float fj = bf2f(xB[jj << 6]);               // lanes contiguous (128B/wave)
                    mx = fmaxf(mx, pv[j] + fj);
                }
            }
            y_t[(nn << 6) + (c ^ ((nn & 7) << 3))] = f2bf(mx);
        }
    }

    int l15 = lane & 15, kg = lane >> 4;
    int nt = wv;

    // ---- stage 2: z[m][nn] = relu(bnp1(Wp1 @ y)), store bf16 z_t[nn][m] ----
    {
        bf16x8 bfr[2];
        #pragma unroll
        for (int ks = 0; ks < 2; ++ks) {
            int row = (nt << 4) + l15;
            bfr[ks] = *(const bf16x8*)&y_t[(row << 6) + (((ks << 5) + (kg << 3)) ^ ((row & 7) << 3))];
        }
        #pragma unroll
        for (int mt = 0; mt < 16; ++mt) {
            f32x4 acc = {0.f, 0.f, 0.f, 0.f};
            #pragma unroll
            for (int ks = 0; ks < 2; ++ks) {
                bf16x8 afr = *(const bf16x8*)&Wp1b[(((mt << 4) + l15) << 6) + (ks << 5) + (kg << 3)];
                acc = __builtin_amdgcn_mfma_f32_16x16x32_bf16(afr, bfr[ks], acc, 0, 0, 0);
            }
            int nn = (nt << 4) + l15;       // D col
            int m0 = (mt << 4) + (kg << 2); // D rows m0..m0+3
            u16x4 zv;
            zv.x = f2bf(fmaxf(fmaf(acc[0], cst[128 + m0 + 0], cst[384 + m0 + 0]), 0.f));
            zv.y = f2bf(fmaxf(fmaf(acc[1], cst[128 + m0 + 1], cst[384 + m0 + 1]), 0.f));
            zv.z = f2bf(fmaxf(fmaf(acc[2], cst[128 + m0 + 2], cst[384 + m0 + 2]), 0.f));
            zv.w = f2bf(fmaxf(fmaf(acc[3], cst[128 + m0 + 3], cst[384 + m0 + 3]), 0.f));
            *(u16x4*)&z_t[(nn << 8) + (m0 ^ ((nn & 7) << 3))] = zv;
        }
    }

    // ---- stage 3: out[o][nn] = relu(bnp2(Wp2 @ z) + f), K=256 ----
    {
        bf16x8 bfr[8];
        #pragma unroll
        for (int ks = 0; ks < 8; ++ks) {
            int row = (nt << 4) + l15;
            bfr[ks] = *(const bf16x8*)&z_t[(row << 8) + (((ks << 5) + (kg << 3)) ^ ((row & 7) << 3))];
        }
        #pragma unroll
        for (int ot = 0; ot < 4; ++ot) {
            f32x4 acc = {0.f, 0.f, 0.f, 0.f};
            int oa = (ot << 4) + l15;   // A row (Wp2 row o)
            #pragma unroll
            for (int ks = 0; ks < 8; ++ks) {
                bf16x8 afr = *(const bf16x8*)&Wp2b[(oa << 8) + (ks << 5) + (kg << 3)];
                acc = __builtin_amdgcn_mfma_f32_16x16x32_bf16(afr, bfr[ks], acc, 0, 0, 0);
            }
            int nn = (nt << 4) + l15;
            int o0 = (ot << 4) + (kg << 2);
            #pragma unroll
            for (int r = 0; r < 4; ++r) {
                int o = o0 + r;
                int off = ((b << 6) + o) * 16384 + n0 + nn;
                float v = fmaf(acc[r], cst[640 + o], cst[704 + o]) + f[off];
                out[off] = fmaxf(v, 0.f);
            }
        }
    }
}

extern "C" void kernel_launch(void* const* d_in, const int* in_sizes, int n_in,
                              void* d_out, int out_size, void* d_ws, size_t ws_size,
                              hipStream_t stream) {
    const float* f   = (const float*)d_in[1];
    const float* pe  = (const float*)d_in[2];
    const int*   idx = (const int*)d_in[3];
    const float* W1  = (const float*)d_in[4];
    const float* g1  = (const float*)d_in[5];
    const float* b1  = (const float*)d_in[6];
    const float* m1  = (const float*)d_in[7];
    const float* v1  = (const float*)d_in[8];
    const float* Wp1 = (const float*)d_in[9];
    const float* gp1 = (const float*)d_in[10];
    const float* bp1 = (const float*)d_in[11];
    const float* mp1 = (const float*)d_in[12];
    const float* vp1 = (const float*)d_in[13];
    const float* Wp2 = (const float*)d_in[14];
    const float* gp2 = (const float*)d_in[15];
    const float* bp2 = (const float*)d_in[16];
    const float* mp2 = (const float*)d_in[17];
    const float* vp2 = (const float*)d_in[18];
    float* out = (float*)d_out;

    char* ws = (char*)d_ws;
    u16*   x1tb  = (u16*)ws;                                   // 8*16384*64*2 = 16,777,216 B
    u16*   W1b   = (u16*)(ws + 16777216);                      // 8,192 B
    u16*   Wp1b  = (u16*)(ws + 16777216 + 8192);               // 32,768 B
    u16*   Wp2b  = (u16*)(ws + 16777216 + 8192 + 32768);       // 32,768 B
    float* cst   = (float*)(ws + 16777216 + 8192 + 32768 + 32768);  // 768 floats

    k_setup<<<64, 256, 0, stream>>>(W1, g1, b1, m1, v1, Wp1, gp1, bp1, mp1, vp1,
                                    Wp2, gp2, bp2, mp2, vp2, W1b, Wp1b, Wp2b, cst);
    k_conv1<<<2048, 256, 0, stream>>>(f, W1b, cst, x1tb);
    k_fused<<<2048, 256, 0, stream>>>(pe, idx, x1tb, f, Wp1b, Wp2b, cst, out);
}

// Round 8
// 834.712 us; speedup vs baseline: 1.0601x; 1.0601x over previous
//
#include <hip/hip_runtime.h>

#define BN_EPS 1e-5f

typedef __attribute__((ext_vector_type(4))) float f32x4;
typedef __attribute__((ext_vector_type(4))) int i32x4;
typedef __attribute__((ext_vector_type(8))) short bf16x8;
typedef __attribute__((ext_vector_type(4))) unsigned short u16x4;
typedef unsigned short u16;

__device__ __forceinline__ u16 f2bf(float x) {
    union { float f; unsigned u; } v; v.f = x;
    unsigned u = v.u;
    return (u16)((u + 0x7FFFu + ((u >> 16) & 1u)) >> 16);  // round-to-nearest-even
}
__device__ __forceinline__ float bf2f(u16 b) {
    union { unsigned u; float f; } v; v.u = ((unsigned)b) << 16;
    return v.f;
}

// ---------------- setup: fold BN into scale/bias, cast weights to bf16 ----------------
__global__ __launch_bounds__(256) void k_setup(
    const float* __restrict__ W1, const float* __restrict__ g1, const float* __restrict__ b1,
    const float* __restrict__ m1, const float* __restrict__ v1,
    const float* __restrict__ Wp1, const float* __restrict__ gp1, const float* __restrict__ bp1,
    const float* __restrict__ mp1, const float* __restrict__ vp1,
    const float* __restrict__ Wp2, const float* __restrict__ gp2, const float* __restrict__ bp2,
    const float* __restrict__ mp2, const float* __restrict__ vp2,
    u16* __restrict__ W1b, u16* __restrict__ Wp1b, u16* __restrict__ Wp2b,
    float* __restrict__ cst) {
    int t = blockIdx.x * 256 + threadIdx.x;
    if (t < 4096)  W1b[t]  = f2bf(W1[t]);
    if (t < 16384) { Wp1b[t] = f2bf(Wp1[t]); Wp2b[t] = f2bf(Wp2[t]); }
    if (t < 64)  { float iv = g1[t]  / sqrtf(v1[t]  + BN_EPS); cst[t]      = iv; cst[64 + t]  = b1[t]  - m1[t]  * iv; }
    if (t < 256) { float iv = gp1[t] / sqrtf(vp1[t] + BN_EPS); cst[128 + t] = iv; cst[384 + t] = bp1[t] - mp1[t] * iv; }
    if (t < 64)  { float iv = gp2[t] / sqrtf(vp2[t] + BN_EPS); cst[640 + t] = iv; cst[704 + t] = bp2[t] - mp2[t] * iv; }
}

// ---------------- conv1: x1t[b][n][c] = bf16( relu(bn1(W1 @ f)) ) ----------------
__global__ __launch_bounds__(256) void k_conv1(
    const float* __restrict__ f, const u16* __restrict__ W1b,
    const float* __restrict__ cst, u16* __restrict__ x1tb) {
    int bid = blockIdx.x;
    int s = ((bid & 7) << 8) | (bid >> 3);   // XCD b -> batch b
    int b = s >> 8;
    int n0 = (s & 255) << 6;
    __shared__ __align__(16) u16 f_t[64 * 64];   // [nn][c] bf16, elem ^= (nn&7)<<3
    int tid = threadIdx.x;
    const float* fB = f + ((b << 6) * 16384 + n0);
    #pragma unroll
    for (int i = 0; i < 4; ++i) {
        int g = tid + (i << 8);
        int c = g >> 4, q = (g & 15) << 2;
        f32x4 v = *(const f32x4*)(fB + c * 16384 + q);
        #pragma unroll
        for (int j = 0; j < 4; ++j) {
            int nn = q + j;
            f_t[(nn << 6) + (c ^ ((nn & 7) << 3))] = f2bf(v[j]);
        }
    }
    __syncthreads();
    int lane = tid & 63, wv = tid >> 6;
    int l15 = lane & 15, kg = lane >> 4;
    int nt = wv;
    bf16x8 afr[2];
    #pragma unroll
    for (int ks = 0; ks < 2; ++ks) {
        int row = (nt << 4) + l15;
        afr[ks] = *(const bf16x8*)&f_t[(row << 6) + (((ks << 5) + (kg << 3)) ^ ((row & 7) << 3))];
    }
    #pragma unroll
    for (int ot = 0; ot < 4; ++ot) {
        f32x4 acc = {0.f, 0.f, 0.f, 0.f};
        int o = (ot << 4) + l15;
        #pragma unroll
        for (int ks = 0; ks < 2; ++ks) {
            bf16x8 bfr = *(const bf16x8*)&W1b[(o << 6) + (ks << 5) + (kg << 3)];
            acc = __builtin_amdgcn_mfma_f32_16x16x32_bf16(afr[ks], bfr, acc, 0, 0, 0);
        }
        float iv = cst[o], be = cst[64 + o];
        #pragma unroll
        for (int r = 0; r < 4; ++r) {
            int nn = (nt << 4) + (kg << 2) + r;
            float x = fmaxf(fmaf(acc[r], iv, be), 0.f);
            x1tb[((b * 16384 + n0 + nn) << 6) + o] = f2bf(x);
        }
    }
}

// ---------------- fused: gather+maxpool -> pwconv1(+bn,relu) -> pwconv2(+bn) + residual + relu ----
// Wave w owns n-rows [16w,16w+16) through all stages => all LDS use is wave-local (no barriers).
__global__ __launch_bounds__(256) void k_fused(
    const float* __restrict__ pe, const int* __restrict__ idx, const u16* __restrict__ x1tb,
    const float* __restrict__ f, const u16* __restrict__ Wp1b, const u16* __restrict__ Wp2b,
    const float* __restrict__ cst, float* __restrict__ out) {
    int bid = blockIdx.x;
    int s = ((bid & 7) << 8) | (bid >> 3);   // XCD b caches x1tb slice of batch b in its L2
    int b = s >> 8;
    int n0 = (s & 255) << 6;
    __shared__ __align__(16) u16 y_t[64 * 64];    // [nn][c]  bf16, elem ^= (nn&7)<<3   (8 KB)
    __shared__ __align__(16) u16 z_t[64 * 256];   // [nn][m]  bf16, elem ^= (nn&7)<<3   (32 KB)
    __shared__ __align__(16) int idx_s[4][256];   // per-wave idx stage                 (4 KB)
    int tid = threadIdx.x;
    int lane = tid & 63, wv = tid >> 6;

    // ---- stage 1: gather + max-pool over K=16 ----
    {
        int c = lane;
        const float* peB = pe + (size_t)(((b << 6) + c) * 16384 + n0) * 16;
        const u16* xB = x1tb + ((b * 16384) << 6) + c;
        const int* idxB = idx + ((b * 16384 + n0) << 4);
        // hoist this wave's 256 idx values: one coalesced 16B/lane load -> LDS
        // (wave-local write->read, no barrier needed)
        *(i32x4*)&idx_s[wv][lane << 2] = *(const i32x4*)&idxB[(wv << 8) + (lane << 2)];
        #pragma unroll 2
        for (int ln = 0; ln < 16; ++ln) {
            int nn = (wv << 4) + ln;
            float mx = -3.4e38f;
            #pragma unroll
            for (int k4 = 0; k4 < 4; ++k4) {
                f32x4 pv = *(const f32x4*)(peB + (nn << 4) + (k4 << 2));
                #pragma unroll
                for (int j = 0; j < 4; ++j) {
                    int jj = idx_s[wv][(ln << 4) + (k4 << 2) + j];  // uniform -> LDS broadcast
                    float fj = bf2f(xB[jj << 6]);                   // lanes contiguous (128B/wave)
                    mx = fmaxf(mx, pv[j] + fj);
                }
            }
            y_t[(nn << 6) + (c ^ ((nn & 7) << 3))] = f2bf(mx);
        }
    }

    int l15 = lane & 15, kg = lane >> 4;
    int nt = wv;

    // ---- stage 2: z[m][nn] = relu(bnp1(Wp1 @ y)), store bf16 z_t[nn][m] ----
    {
        bf16x8 bfr[2];
        #pragma unroll
        for (int ks = 0; ks < 2; ++ks) {
            int row = (nt << 4) + l15;
            bfr[ks] = *(const bf16x8*)&y_t[(row << 6) + (((ks << 5) + (kg << 3)) ^ ((row & 7) << 3))];
        }
        #pragma unroll
        for (int mt = 0; mt < 16; ++mt) {
            f32x4 acc = {0.f, 0.f, 0.f, 0.f};
            #pragma unroll
            for (int ks = 0; ks < 2; ++ks) {
                bf16x8 afr = *(const bf16x8*)&Wp1b[(((mt << 4) + l15) << 6) + (ks << 5) + (kg << 3)];
                acc = __builtin_amdgcn_mfma_f32_16x16x32_bf16(afr, bfr[ks], acc, 0, 0, 0);
            }
            int nn = (nt << 4) + l15;       // D col
            int m0 = (mt << 4) + (kg << 2); // D rows m0..m0+3
            u16x4 zv;
            zv.x = f2bf(fmaxf(fmaf(acc[0], cst[128 + m0 + 0], cst[384 + m0 + 0]), 0.f));
            zv.y = f2bf(fmaxf(fmaf(acc[1], cst[128 + m0 + 1], cst[384 + m0 + 1]), 0.f));
            zv.z = f2bf(fmaxf(fmaf(acc[2], cst[128 + m0 + 2], cst[384 + m0 + 2]), 0.f));
            zv.w = f2bf(fmaxf(fmaf(acc[3], cst[128 + m0 + 3], cst[384 + m0 + 3]), 0.f));
            *(u16x4*)&z_t[(nn << 8) + (m0 ^ ((nn & 7) << 3))] = zv;
        }
    }

    // ---- stage 3: out[o][nn] = relu(bnp2(Wp2 @ z) + f), K=256 ----
    {
        bf16x8 bfr[8];
        #pragma unroll
        for (int ks = 0; ks < 8; ++ks) {
            int row = (nt << 4) + l15;
            bfr[ks] = *(const bf16x8*)&z_t[(row << 8) + (((ks << 5) + (kg << 3)) ^ ((row & 7) << 3))];
        }
        #pragma unroll
        for (int ot = 0; ot < 4; ++ot) {
            f32x4 acc = {0.f, 0.f, 0.f, 0.f};
            int oa = (ot << 4) + l15;   // A row (Wp2 row o)
            #pragma unroll
            for (int ks = 0; ks < 8; ++ks) {
                bf16x8 afr = *(const bf16x8*)&Wp2b[(oa << 8) + (ks << 5) + (kg << 3)];
                acc = __builtin_amdgcn_mfma_f32_16x16x32_bf16(afr, bfr[ks], acc, 0, 0, 0);
            }
            int nn = (nt << 4) + l15;
            int o0 = (ot << 4) + (kg << 2);
            #pragma unroll
            for (int r = 0; r < 4; ++r) {
                int o = o0 + r;
                int off = ((b << 6) + o) * 16384 + n0 + nn;
                float v = fmaf(acc[r], cst[640 + o], cst[704 + o]) + f[off];
                out[off] = fmaxf(v, 0.f);
            }
        }
    }
}

extern "C" void kernel_launch(void* const* d_in, const int* in_sizes, int n_in,
                              void* d_out, int out_size, void* d_ws, size_t ws_size,
                              hipStream_t stream) {
    const float* f   = (const float*)d_in[1];
    const float* pe  = (const float*)d_in[2];
    const int*   idx = (const int*)d_in[3];
    const float* W1  = (const float*)d_in[4];
    const float* g1  = (const float*)d_in[5];
    const float* b1  = (const float*)d_in[6];
    const float* m1  = (const float*)d_in[7];
    const float* v1  = (const float*)d_in[8];
    const float* Wp1 = (const float*)d_in[9];
    const float* gp1 = (const float*)d_in[10];
    const float* bp1 = (const float*)d_in[11];
    const float* mp1 = (const float*)d_in[12];
    const float* vp1 = (const float*)d_in[13];
    const float* Wp2 = (const float*)d_in[14];
    const float* gp2 = (const float*)d_in[15];
    const float* bp2 = (const float*)d_in[16];
    const float* mp2 = (const float*)d_in[17];
    const float* vp2 = (const float*)d_in[18];
    float* out = (float*)d_out;

    char* ws = (char*)d_ws;
    u16*   x1tb  = (u16*)ws;                                   // 16,777,216 B
    u16*   W1b   = (u16*)(ws + 16777216);                      // 8,192 B
    u16*   Wp1b  = (u16*)(ws + 16777216 + 8192);               // 32,768 B
    u16*   Wp2b  = (u16*)(ws + 16777216 + 8192 + 32768);       // 32,768 B
    float* cst   = (float*)(ws + 16777216 + 8192 + 32768 + 32768);  // 768 floats

    k_setup<<<64, 256, 0, stream>>>(W1, g1, b1, m1, v1, Wp1, gp1, bp1, mp1, vp1,
                                    Wp2, gp2, bp2, mp2, vp2, W1b, Wp1b, Wp2b, cst);
    k_conv1<<<2048, 256, 0, stream>>>(f, W1b, cst, x1tb);
    k_fused<<<2048, 256, 0, stream>>>(pe, idx, x1tb, f, Wp1b, Wp2b, cst, out);
}